// Round 5
// baseline (384.290 us; speedup 1.0000x reference)
//
#include <hip/hip_runtime.h>

typedef unsigned short u16;
typedef unsigned int   u32;
typedef unsigned long long u64;
typedef unsigned char  u8;
typedef __attribute__((ext_vector_type(8))) short bf16x8;
typedef __attribute__((ext_vector_type(4))) float f32x4;

#define B_  4
#define S_  2048
#define D_  1024
#define H_  16
#define DH_ 64

#define MFMA16 __builtin_amdgcn_mfma_f32_16x16x32_bf16

// counted vmcnt wait + scheduler fence (rule #18)
#define WAITV(NSTR) do {                                   \
    asm volatile("s_waitcnt vmcnt(" NSTR ")" ::: "memory");\
    __builtin_amdgcn_sched_barrier(0);                     \
  } while (0)

__device__ __forceinline__ u16 f2bf(float f) {
  u32 u = __builtin_bit_cast(u32, f);
  u32 r = (u + 0x7FFFu + ((u >> 16) & 1u)) >> 16;   // RNE
  return (u16)r;
}

__device__ __forceinline__ u32 cvt_pk_bf16(float lo, float hi) {
  u32 r;
  asm("v_cvt_pk_bf16_f32 %0, %1, %2" : "=v"(r) : "v"(lo), "v"(hi));
  return r;
}

__device__ __forceinline__ float exp2_fast(float x) {   // 2^x
  float r;
  asm("v_exp_f32 %0, %1" : "=v"(r) : "v"(x));
  return r;
}

__device__ __forceinline__ void gload_lds16(const void* g, void* l) {
  __builtin_amdgcn_global_load_lds(
      (const __attribute__((address_space(1))) u32*)g,
      (__attribute__((address_space(3))) u32*)l,
      16, 0, 0);
}

// swizzled LDS fragment read: 16B at (row, colbyte cb), rows are 128B
__device__ __forceinline__ bf16x8 lds_frag(const u16* base, int row, int cb) {
  return *(const bf16x8*)((const char*)base + row * 128 + (cb ^ ((row & 7) << 4)));
}

// ---------------- prep: X->bf16 | mask->bitmask | bias fuse ----------------
__global__ __launch_bounds__(256) void prep(
    const float* __restrict__ x, u16* __restrict__ xb,
    const int* __restrict__ m, u64* __restrict__ mbw,
    const float* __restrict__ bq, const float* __restrict__ bk,
    const float* __restrict__ bv, float* __restrict__ fb) {
  const int blk = blockIdx.x;
  if (blk < 8192) {                       // X f32 -> bf16 (8.39M elems)
    const int i = (blk * 256 + threadIdx.x) * 4;
    float4 v = *(const float4*)(x + i);
    ushort4 o;
    o.x = f2bf(v.x); o.y = f2bf(v.y); o.z = f2bf(v.z); o.w = f2bf(v.w);
    *(ushort4*)(xb + i) = o;
  } else if (blk < 8192 + 2048) {         // mask int32 -> u64 bitmask
    const int base = (blk - 8192) * 2048;
#pragma unroll
    for (int it = 0; it < 8; it++) {
      const int i = base + it * 256 + threadIdx.x;
      const u64 bits = __ballot(m[i] != 0);
      if ((threadIdx.x & 63) == 0) mbw[i >> 6] = bits;
    }
  } else {                                // fused bias [3072]
    const int i = (blk - 10240) * 256 + threadIdx.x;
    fb[i] = i < 1024 ? bq[i] : (i < 2048 ? bk[i - 1024] : bv[i - 2048]);
  }
}

// ---------------- prep: W[k][n] f32 -> Wt[n][k] bf16 ----------------
__global__ __launch_bounds__(256) void transpose_w(
    const float* __restrict__ W0, const float* __restrict__ W1,
    const float* __restrict__ W2, const float* __restrict__ W3,
    u16* __restrict__ T0, u16* __restrict__ T1,
    u16* __restrict__ T2, u16* __restrict__ T3) {
  __shared__ float t[64][65];
  const int z = blockIdx.z;
  const float* W = z == 0 ? W0 : z == 1 ? W1 : z == 2 ? W2 : W3;
  u16* T        = z == 0 ? T0 : z == 1 ? T1 : z == 2 ? T2 : T3;
  const int n0 = blockIdx.x * 64, k0 = blockIdx.y * 64;
  const int c = threadIdx.x & 63, r0 = threadIdx.x >> 6;
#pragma unroll
  for (int i = 0; i < 16; i++)
    t[r0 + i * 4][c] = W[(size_t)(k0 + r0 + i * 4) * 1024 + n0 + c];
  __syncthreads();
#pragma unroll
  for (int i = 0; i < 16; i++)
    T[(size_t)(n0 + r0 + i * 4) * 1024 + k0 + c] = f2bf(t[c][r0 + i * 4]);
}

// ---------------- GEMM: C[8192,N] = A[8192,1024] @ Bt[N,1024]^T + bias --------
// mode 3: fused QKV (N=3072, grid 1536 1D): bf16 out into q/k/vt (outp = q base)
// mode 2: f32 out, row-major [m][1024] (final projection, grid 512 1D)
__global__ __launch_bounds__(256) void gemm_bt(
    const u16* __restrict__ A, const u16* __restrict__ Bw,
    const float* __restrict__ bias, void* __restrict__ outp,
    int mode, int chunk) {
  __shared__ u16 As[2][128 * 32];
  __shared__ u16 Bs[2][128 * 32];
  const int tid = threadIdx.x;
  const int lane = tid & 63, wid = tid >> 6;
  const int wr = wid >> 1, wc = wid & 1;
  // XCD swizzle: consecutive sid share bn -> B-panel stays in one XCD's L2
  const int sid = (blockIdx.x & 7) * chunk + (blockIdx.x >> 3);
  const int bm = sid & 63, bn = sid >> 6;
  const int lr = lane & 15, lk8 = (lane >> 4) * 8, lg = (lane >> 4) * 4;

  f32x4 acc[4][4];
#pragma unroll
  for (int i = 0; i < 4; i++)
#pragma unroll
    for (int j = 0; j < 4; j++) acc[i][j] = (f32x4){0.f, 0.f, 0.f, 0.f};

  const int r0 = tid >> 2;            // tile row (of 128), rows are 32 bf16 = 64B
  const int c0 = (tid & 3) * 8;       // elem col within row
  const u16* gA = A + ((size_t)(bm * 128 + r0) << 10) + c0;
  const u16* gB = Bw + ((size_t)(bn * 128 + r0) << 10) + c0;

#define GSTAGE(ki, bf) do {                                        \
    const int kt_ = (ki) * 32;                                     \
    gload_lds16(gA + kt_, &As[bf][tid * 8]);                       \
    gload_lds16(gA + kt_ + (64 << 10), &As[bf][tid * 8 + 64 * 32]);\
    gload_lds16(gB + kt_, &Bs[bf][tid * 8]);                       \
    gload_lds16(gB + kt_ + (64 << 10), &Bs[bf][tid * 8 + 64 * 32]);\
  } while (0)

  GSTAGE(0, 0);

  for (int ki = 0; ki < 32; ki++) {
    const int cur = ki & 1;
    __builtin_amdgcn_sched_barrier(0);
    if (ki + 1 < 32) {
      GSTAGE(ki + 1, cur ^ 1);   // loads stay in flight across the barrier
      WAITV("4");                // oldest 4 (= tile ki) complete; tile ki+1 in flight
    } else {
      WAITV("0");
    }
    __builtin_amdgcn_s_barrier();
    __builtin_amdgcn_sched_barrier(0);

    bf16x8 af[4], bfr[4];
#pragma unroll
    for (int mr = 0; mr < 4; mr++)
      af[mr] = *(const bf16x8*)&As[cur][(wr * 64 + mr * 16 + lr) * 32 + lk8];
#pragma unroll
    for (int nr = 0; nr < 4; nr++)
      bfr[nr] = *(const bf16x8*)&Bs[cur][(wc * 64 + nr * 16 + lr) * 32 + lk8];
    __builtin_amdgcn_s_setprio(1);
#pragma unroll
    for (int mr = 0; mr < 4; mr++)
#pragma unroll
      for (int nr = 0; nr < 4; nr++)
        acc[mr][nr] = MFMA16(af[mr], bfr[nr], acc[mr][nr], 0, 0, 0);
    __builtin_amdgcn_s_setprio(0);
    __builtin_amdgcn_s_barrier();   // all waves done reading As/Bs[cur]
  }

#pragma unroll
  for (int mr = 0; mr < 4; mr++) {
#pragma unroll
    for (int nr = 0; nr < 4; nr++) {
      const int n = bn * 128 + wc * 64 + nr * 16 + lr;
      const float bv = bias[n];
#pragma unroll
      for (int r = 0; r < 4; r++) {
        const int m = bm * 128 + wr * 64 + mr * 16 + lg + r;
        float v = acc[mr][nr][r] + bv;
        if (mode == 2) {
          ((float*)outp)[(size_t)m * 1024 + n] = v;
        } else {
          const int which = n >> 10, col = n & 1023;
          const int bb = m >> 11, s = m & (S_ - 1);
          const int hh = col >> 6, dh = col & (DH_ - 1);
          if (which == 0) v *= 0.180336880f;   // (1/sqrt(64)) * log2(e)
          u16* o = (u16*)outp + ((size_t)which << 23);   // +16MB per tensor
          if (which <= 1)
            o[((((size_t)bb * H_ + hh) * S_ + s) << 6) + dh] = f2bf(v);     // Q,K
          else
            o[(((size_t)(bb * H_ + hh) * DH_ + dh) << 11) + s] = f2bf(v);   // V^T
        }
      }
    }
  }
}

// ---------------- flash attention: swapped QK^T, lane-local softmax ----------------
// 1D grid 2048 (XCD-swizzled), 256 threads = 4 waves, wave w owns 16 q rows
__global__ __launch_bounds__(256) void attn(
    const u16* __restrict__ Q, const u16* __restrict__ K,
    const u16* __restrict__ Vt, const u64* __restrict__ mb,
    u16* __restrict__ ctx) {
  __shared__ u16 Kl[2][64 * 64];
  __shared__ u16 Vl[2][64 * 64];
  __shared__ u16 Pl[4][16 * 64];

  const int tid = threadIdx.x, lane = tid & 63, wid = tid >> 6;
  // XCD swizzle: each XCD gets 256 consecutive sid = 8 (b,h) groups -> K/V L2-resident
  const int sid = (blockIdx.x & 7) * 256 + (blockIdx.x >> 3);
  const int q0 = (sid & 31) * 64;
  const int h = (sid >> 5) & 15, b = sid >> 9;
  const size_t bh = (size_t)b * H_ + h;
  const u16* Qb = Q + (bh * S_ << 6);
  const u16* Kb = K + (bh * S_ << 6);
  const u16* Vb = Vt + (bh * DH_ << 11);
  const int qh = lane & 15, g = lane >> 4, lk8 = g * 8;
  const int qrow = q0 + wid * 16 + qh;      // this lane's softmax row

  const bf16x8 qf0 = *(const bf16x8*)(Qb + ((size_t)qrow << 6) + lk8);
  const bf16x8 qf1 = *(const bf16x8*)(Qb + ((size_t)qrow << 6) + 32 + lk8);

  f32x4 acc[4];                              // acc[nc][r]: O[q=g*4+r][d=nc*16+qh]
#pragma unroll
  for (int i = 0; i < 4; i++) acc[i] = (f32x4){0.f, 0.f, 0.f, 0.f};
  float mrun = -1e30f, lsum = 0.f;           // lsum: PER-LANE partial (reduced at end)

  const int sr = tid >> 3;                   // staging row, rows are 128B
  const int scz = ((((tid & 7) * 16) ^ ((sr & 7) << 4)) >> 1);   // pre-swizzled col

#define ASTAGE(t, bf) do {                                                  \
    const int kt_ = (t) * 64;                                               \
    gload_lds16(Kb + ((size_t)(kt_ + sr) << 6) + scz, &Kl[bf][tid * 8]);    \
    gload_lds16(Kb + ((size_t)(kt_ + sr + 32) << 6) + scz,                  \
                &Kl[bf][tid * 8 + 32 * 64]);                                \
    gload_lds16(Vb + ((size_t)sr << 11) + kt_ + scz, &Vl[bf][tid * 8]);     \
    gload_lds16(Vb + ((size_t)(sr + 32) << 11) + kt_ + scz,                 \
                &Vl[bf][tid * 8 + 32 * 64]);                                \
  } while (0)

  ASTAGE(0, 0);

  for (int t = 0; t < S_ / 64; t++) {
    const int cur = t & 1;
    __builtin_amdgcn_sched_barrier(0);
    if (t + 1 < S_ / 64) {
      ASTAGE(t + 1, cur ^ 1);
      WAITV("4");              // tile t landed; tile t+1 stays in flight
    } else {
      WAITV("0");
    }
    __builtin_amdgcn_s_barrier();
    __builtin_amdgcn_sched_barrier(0);

    const u64 mw = mb[((size_t)qrow << 5) + t];   // mask bits for this lane's q-row

    // QK^T swapped: sc[nr][r] = S[k = nr*16 + g*4 + r][q = qh]
    f32x4 sc[4];
    __builtin_amdgcn_s_setprio(1);
#pragma unroll
    for (int nr = 0; nr < 4; nr++) {
      const int row = nr * 16 + qh;
      const bf16x8 kf0 = lds_frag(Kl[cur], row, lk8 * 2);
      const bf16x8 kf1 = lds_frag(Kl[cur], row, 64 + lk8 * 2);
      f32x4 z = (f32x4){0.f, 0.f, 0.f, 0.f};
      z = MFMA16(kf0, qf0, z, 0, 0, 0);
      z = MFMA16(kf1, qf1, z, 0, 0, 0);
      sc[nr] = z;
    }
    __builtin_amdgcn_s_setprio(0);

    // in-lane max over all 16 (mask-agnostic: max over superset >= true max, safe)
    float tmax = fmaxf(fmaxf(sc[0][0], sc[0][1]), sc[0][2]);
    tmax = fmaxf(fmaxf(tmax, sc[0][3]), fmaxf(sc[1][0], sc[1][1]));
    tmax = fmaxf(fmaxf(tmax, sc[1][2]), fmaxf(sc[1][3], sc[2][0]));
    tmax = fmaxf(fmaxf(tmax, sc[2][1]), fmaxf(sc[2][2], sc[2][3]));
    tmax = fmaxf(fmaxf(tmax, sc[3][0]), fmaxf(sc[3][1], sc[3][2]));
    tmax = fmaxf(tmax, sc[3][3]);

    // lazy defer-max: cross-lane reduce + rescale only on trigger (rare)
    if (!__all(tmax <= mrun + 8.0f)) {
      float tq = fmaxf(tmax, __shfl_xor(tmax, 16));
      tq = fmaxf(tq, __shfl_xor(tq, 32));
      const float mnew = fmaxf(mrun, tq);
      const float alpha = exp2_fast(mrun - mnew);
      lsum *= alpha;
      mrun = mnew;
#pragma unroll
      for (int r = 0; r < 4; r++) {
        const float as = __shfl(alpha, g * 4 + r);   // alpha for slot-row q=g*4+r
        acc[0][r] *= as; acc[1][r] *= as; acc[2][r] *= as; acc[3][r] *= as;
      }
    }

    // P = 2^(s-m) zeroed by mask bit, per-lane partial sum, pack bf16 pairs
    const u64 mwg = mw >> (g * 4);
    const u32 mlo = (u32)mwg, mhi = (u32)(mwg >> 32);
    float ts = 0.f;
    u32 w[8];
#pragma unroll
    for (int nr = 0; nr < 4; nr++) {
      const u32 wsel = (nr & 2) ? mhi : mlo;
      const int sh = (nr & 1) * 16;
      float p0 = exp2_fast(sc[nr][0] - mrun);
      float p1 = exp2_fast(sc[nr][1] - mrun);
      float p2 = exp2_fast(sc[nr][2] - mrun);
      float p3 = exp2_fast(sc[nr][3] - mrun);
      p0 = ((wsel >> (sh + 0)) & 1u) ? p0 : 0.f;
      p1 = ((wsel >> (sh + 1)) & 1u) ? p1 : 0.f;
      p2 = ((wsel >> (sh + 2)) & 1u) ? p2 : 0.f;
      p3 = ((wsel >> (sh + 3)) & 1u) ? p3 : 0.f;
      ts += (p0 + p1) + (p2 + p3);
      w[nr * 2]     = cvt_pk_bf16(p0, p1);
      w[nr * 2 + 1] = cvt_pk_bf16(p2, p3);
    }
    lsum += ts;

    // P -> per-wave LDS (swizzled b32 writes; 2-way bank alias = free)
    {
      char* pw = (char*)Pl[wid] + qh * 128;
      const int sw = (qh & 7) << 4;
#pragma unroll
      for (int nr = 0; nr < 4; nr++) {
        *(u32*)(pw + ((g * 8 + nr * 32) ^ sw))     = w[nr * 2];
        *(u32*)(pw + ((g * 8 + 4 + nr * 32) ^ sw)) = w[nr * 2 + 1];
      }
    }

    // PV: acc[nc] += P[q][k] * V^T[d][k]
#pragma unroll
    for (int ks = 0; ks < 2; ks++) {
      const bf16x8 pf = lds_frag(Pl[wid], qh, ks * 64 + lk8 * 2);
      __builtin_amdgcn_s_setprio(1);
#pragma unroll
      for (int nc = 0; nc < 4; nc++) {
        const bf16x8 vf = lds_frag(Vl[cur], nc * 16 + qh, ks * 64 + lk8 * 2);
        acc[nc] = MFMA16(pf, vf, acc[nc], 0, 0, 0);
      }
      __builtin_amdgcn_s_setprio(0);
    }
    __builtin_amdgcn_s_barrier();   // all waves done reading Kl/Vl[cur]
  }

  // epilogue: cross-lane lsum reduce once, then ctx[b][s][h*DH+d]
  float lt = lsum + __shfl_xor(lsum, 16);
  lt += __shfl_xor(lt, 32);
  float linv[4];
#pragma unroll
  for (int r = 0; r < 4; r++) linv[r] = 1.0f / __shfl(lt, g * 4 + r);
#pragma unroll
  for (int nc = 0; nc < 4; nc++)
#pragma unroll
    for (int r = 0; r < 4; r++) {
      const float o = acc[nc][r] * linv[r];
      const int ql = q0 + wid * 16 + g * 4 + r;
      ctx[((size_t)b * S_ + ql) * D_ + h * DH_ + nc * 16 + qh] = f2bf(o);
    }
}

extern "C" void kernel_launch(void* const* d_in, const int* in_sizes, int n_in,
                              void* d_out, int out_size, void* d_ws, size_t ws_size,
                              hipStream_t stream) {
  const float* X  = (const float*)d_in[0];
  const int* mask = (const int*)d_in[1];
  const float* Wq = (const float*)d_in[2];
  const float* bq = (const float*)d_in[3];
  const float* Wk = (const float*)d_in[4];
  const float* bk = (const float*)d_in[5];
  const float* Wv = (const float*)d_in[6];
  const float* bv = (const float*)d_in[7];
  const float* Wo = (const float*)d_in[8];
  const float* bo = (const float*)d_in[9];

  char* ws = (char*)d_ws;
  const size_t MB = 1024 * 1024;
  u16* xb  = (u16*)(ws);             // 16MB X bf16; reused as ctx after attn
  u16* q   = (u16*)(ws + 16 * MB);   // 16MB (k, vt follow at +16MB each)
  u16* wqt = (u16*)(ws + 64 * MB);   // 3x2MB contiguous = fused [3072][1024]
  u16* wkt = (u16*)(ws + 66 * MB);
  u16* wvt = (u16*)(ws + 68 * MB);
  u16* wot = (u16*)(ws + 70 * MB);
  u64* mbb = (u64*)(ws + 72 * MB);   // 512KB bitmask
  float* fb = (float*)(ws + 72 * MB + 512 * 1024);  // 12KB fused bias

  prep<<<10252, 256, 0, stream>>>(X, xb, mask, mbb, bq, bk, bv, fb);
  transpose_w<<<dim3(16, 16, 4), 256, 0, stream>>>(Wq, Wk, Wv, Wo, wqt, wkt, wvt, wot);

  gemm_bt<<<1536, 256, 0, stream>>>(xb, wqt, fb, q, 3, 192);         // fused QKV

  u16* k  = q + (1u << 23);
  u16* vt = q + (2u << 23);
  attn<<<2048, 256, 0, stream>>>(q, k, vt, mbb, xb);                 // ctx -> xb

  gemm_bt<<<512, 256, 0, stream>>>(xb, wot, bo, d_out, 2, 64);       // out proj
}